// Round 3
// baseline (108.980 us; speedup 1.0000x reference)
//
#include <hip/hip_runtime.h>
#include <hip/hip_cooperative_groups.h>
#include <math.h>

namespace cg = cooperative_groups;

// Problem constants
#define NVOX  1048576      // voxels per BC slice (64*128*128)
#define MFINE 2048         // fine histogram bins over [0,1]
#define BINS  32
#define PB    64           // hist blocks per slice
#define GRID  256          // 4 slices * 64 hist chunks; also 2 slices * 128 apply chunks
#define NLUT  2048

// d_ws layout (bytes), all regions written before read (no memset needed):
//   [0, 32768) : float partial[4*32][64]  soft-hist partials, [slice_bin][block]

// ---------------------------------------------------------------------------
// Fused cooperative kernel: hist + table + apply in one dispatch.
//
// Phase 1 (hist): block b histograms chunk (b&63) of slice (b>>6) into a
// private LDS fine histogram (2048 bins, LDS atomics), then convolves it with
// f(d) = sig(5(d+.5)) - sig(5(d-.5)) truncated to |d|<=4.5 via the 1-exp
// identity f = E*c1/(1+E*c2+E^2), E strength-reduced (E *= e^{80*DY} replaces
// v_exp_f32 per iter). Partials written transposed [slice_bin][block].
// Each thread ALSO holds its 16-voxel apply chunk (slice b>>7, chunk b&127)
// in registers across the grid sync -- no dst re-read in phase 2.
//
// grid.sync()  (cooperative launch; 256 blocks <= 256 CUs, co-resident)
//
// Phase 2 (table+apply): every block redundantly reduces the partials for its
// apply slice + matching ref slice (16 KB, L2-resident), segmented shuffle
// cumsum -> cdf, argmin matching table, builds a 2048-entry LUT of the full
// voxel->output function in LDS, then applies it to the 16 held voxels with
// linear interpolation and streams the result out (all 256 CUs writing).
// ---------------------------------------------------------------------------
__global__ __launch_bounds__(512) void fused_kernel(const float4* __restrict__ dst4,
                                                    const float4* __restrict__ ref4,
                                                    float* __restrict__ partial,
                                                    float4* __restrict__ out4) {
    __shared__ unsigned int h[MFINE];   // 8 KB
    __shared__ float slut[NLUT];        // 8 KB
    __shared__ float softS[64];         // [0,32) dst bins, [32,64) ref bins
    __shared__ float cdfS[64];
    __shared__ float gS[BINS];          // exp(-k^2/50)
    __shared__ float gtS[BINS];         // g_k * table_k

    const int t  = threadIdx.x;
    const int b  = blockIdx.x;
    const int s  = b >> 6;       // hist slice 0..3
    const int ib = b & 63;       // hist chunk within slice
    const int as_ = b >> 7;      // apply slice 0..1
    const int ia  = b & 127;     // apply chunk within slice

    // ---- issue apply loads first (oldest in flight, held across grid sync) ----
    const int abase = as_ * (NVOX / 4) + ia * 2048;
    float4 a[4];
    #pragma unroll
    for (int j = 0; j < 4; ++j) a[j] = dst4[abase + j * 512 + t];

    // ---- hist loads (8 float4/thread) ----
    const float4* src = (s < 2) ? (dst4 + s * (NVOX / 4))
                                : (ref4 + (s - 2) * (NVOX / 4));
    const int hbase = ib * 4096;   // 4096 float4 per block
    float4 v[8];
    #pragma unroll
    for (int j = 0; j < 8; ++j) v[j] = src[hbase + j * 512 + t];

    for (int i = t; i < MFINE; i += 512) h[i] = 0;
    __syncthreads();

    #pragma unroll
    for (int j = 0; j < 8; ++j) {
        int m0 = min(max((int)(v[j].x * (float)MFINE), 0), MFINE - 1);
        int m1 = min(max((int)(v[j].y * (float)MFINE), 0), MFINE - 1);
        int m2 = min(max((int)(v[j].z * (float)MFINE), 0), MFINE - 1);
        int m3 = min(max((int)(v[j].w * (float)MFINE), 0), MFINE - 1);
        atomicAdd(&h[m0], 1u);
        atomicAdd(&h[m1], 1u);
        atomicAdd(&h[m2], 1u);
        atomicAdd(&h[m3], 1u);
    }
    __syncthreads();

    // ---- per-block conv: 32 bins x 16 lanes each ----
    {
        const int c = t >> 4;       // soft bin 0..31
        const int j = t & 15;
        const float fc = (float)c;
        const float DY = 31.0f / (float)MFINE;     // fine-bin width in y units
        const float c1 = 12.1825190f;              // e^2.5 - e^-2.5
        const float c2 = 12.3467369f;              // e^2.5 + e^-2.5

        int i0 = (int)ceilf((fc - 4.5f) * ((float)MFINE / 31.0f) - 0.5f);
        int i1 = (int)floorf((fc + 4.5f) * ((float)MFINE / 31.0f) - 0.5f);
        if (i0 < 0) i0 = 0;
        if (i1 > MFINE - 1) i1 = MFINE - 1;

        // E = exp(5*d) with d = (i+0.5)*DY - fc; stride 16 => E *= exp(80*DY)
        const float Kstep = __expf(80.0f * DY);
        float d0 = fmaf((float)(i0 + j), DY, 0.5f * DY - fc);
        float E  = __expf(5.0f * d0);

        float acc = 0.f;
        for (int i = i0 + j; i <= i1; i += 16) {
            float cnt = (float)h[i];
            float den = fmaf(E, c2, fmaf(E, E, 1.0f));
            acc = fmaf(cnt * E, c1 * __builtin_amdgcn_rcpf(den), acc);
            E *= Kstep;
        }
        acc += __shfl_xor(acc, 1, 64);
        acc += __shfl_xor(acc, 2, 64);
        acc += __shfl_xor(acc, 4, 64);
        acc += __shfl_xor(acc, 8, 64);
        if (j == 0) partial[(s * BINS + c) * PB + ib] = acc;
    }

    // ---- grid-wide barrier: all partials visible to all blocks ----
    cg::this_grid().sync();

    // ---- reduce partials for apply slice: 64 rows x 8 lanes, 2 float4 each ----
    {
        const int r = t >> 3, j = t & 7;
        const int grow = (r < 32) ? (as_ * BINS + r) : ((2 + as_) * BINS + (r - 32));
        const float4* prow = (const float4*)(partial + grow * PB);
        float4 a4 = make_float4(0.f, 0.f, 0.f, 0.f);
        #pragma unroll
        for (int m = 0; m < 2; ++m) {
            float4 p = prow[j + 8 * m];
            a4.x += p.x; a4.y += p.y; a4.z += p.z; a4.w += p.w;
        }
        float acc = (a4.x + a4.y) + (a4.z + a4.w);
        acc += __shfl_xor(acc, 1, 64);
        acc += __shfl_xor(acc, 2, 64);
        acc += __shfl_xor(acc, 4, 64);
        if (j == 0) softS[r] = acc;
    }
    __syncthreads();

    // ---- segmented (width-32) shuffle prefix-sum + normalize -> cdf ----
    if (t < 64) {
        float v2 = softS[t];
        #pragma unroll
        for (int off = 1; off < BINS; off <<= 1) {
            float w = __shfl_up(v2, off, 32);
            if ((t & 31) >= off) v2 += w;
        }
        float total = __shfl(v2, 31, 32);
        cdfS[t] = v2 / fmaxf(total, 1e-12f);
    }
    __syncthreads();

    // ---- argmin matching table ----
    if (t < 32) {
        float v2 = cdfS[t];
        int best = 0;
        float bd = fabsf(v2 - cdfS[32]);
        #pragma unroll
        for (int k = 1; k < BINS; ++k) {
            float dk = fabsf(v2 - cdfS[32 + k]);
            if (dk < bd) { bd = dk; best = k; }   // strict < keeps lowest index
        }
        float g = __expf(-(float)(t * t) * (1.0f / 50.0f));
        gtS[t] = g * (float)best;
        gS[t]  = g;
    }
    __syncthreads();

    // ---- LUT: out(x) = (Σ_k u_k g_k t_k)/(Σ_k u_k g_k)/31, u_k = r^k,
    //      r = e^{y/25}, y = x*31, sampled at x = idx/2047 ----
    for (int e = t; e < NLUT; e += 512) {
        float y = (float)e * (31.0f / (float)(NLUT - 1));
        float r = __expf(y * (1.0f / 25.0f));
        float u = 1.f, num = 0.f, den = 0.f;
        #pragma unroll
        for (int k = 0; k < BINS; ++k) {
            num = fmaf(u, gtS[k], num);
            den = fmaf(u, gS[k], den);
            u *= r;
        }
        slut[e] = num * __builtin_amdgcn_rcpf(den) * (1.0f / 31.0f);
    }
    __syncthreads();

    // ---- apply: 16 held voxels/thread via LUT + linear interp ----
    float* x = (float*)a;
    #pragma unroll
    for (int i = 0; i < 16; ++i) {
        float p = x[i] * (float)(NLUT - 1);
        p = fminf(fmaxf(p, 0.f), (float)(NLUT - 1) - 1.0f);
        int   ix = (int)p;
        float fr = p - (float)ix;
        float lo = slut[ix], hi = slut[ix + 1];
        x[i] = fmaf(fr, hi - lo, lo);
    }
    #pragma unroll
    for (int j = 0; j < 4; ++j) out4[abase + j * 512 + t] = a[j];
}

// ---------------------------------------------------------------------------
extern "C" void kernel_launch(void* const* d_in, const int* in_sizes, int n_in,
                              void* d_out, int out_size, void* d_ws, size_t ws_size,
                              hipStream_t stream) {
    const float4* dst4 = (const float4*)d_in[0];
    const float4* ref4 = (const float4*)d_in[1];
    float4* out4 = (float4*)d_out;
    float* partial = (float*)d_ws;

    void* args[] = { (void*)&dst4, (void*)&ref4, (void*)&partial, (void*)&out4 };
    hipLaunchCooperativeKernel((const void*)fused_kernel, dim3(GRID), dim3(512),
                               args, 0, stream);
}

// Round 4
// 76.310 us; speedup vs baseline: 1.4281x; 1.4281x over previous
//
#include <hip/hip_runtime.h>
#include <math.h>

// Problem constants
#define NVOX  1048576      // voxels per BC slice (64*128*128)
#define NSLC  4            // dst0, dst1, ref0, ref1
#define MFINE 2048         // fine histogram bins over [0,1]
#define BINS  32
#define PB    64           // hist blocks per slice
#define HIST_BLOCKS  (NSLC * PB)   // 256
#define APPLY_BLOCKS 512           // 2 slices * 1M voxels / (256 thr * 16 vox)
#define NLUT  2048

// d_ws layout (bytes), all regions written before read (no memset needed):
//   [0, 32768) : float partial[4*32][64]  soft-hist partials, [slice_bin][block]

// ---------------------------------------------------------------------------
// K1: private fine histogram per block (LDS atomics), then each block
// convolves its OWN hist with f(d) = sig(5(d+.5)) - sig(5(d-.5)) truncated to
// |d| <= 4.5 (tail < 2e-11), via the 1-exp identity
//   f = E*c1 / (1 + E*c2 + E^2),  E = e^{5d}, c1 = e^2.5-e^-2.5, c2 = e^2.5+e^-2.5
// E is strength-reduced: per-thread fine-bin stride is 16, so E *= e^{80*DY}
// replaces a v_exp_f32 per iteration (only rcp remains transcendental).
// Conv is linear, so sum-of-partials == conv-of-total. Partials are written
// transposed ([slice_bin][block]) for coalesced reduction in K2.
// 512 threads, 64 blocks/slice: 1 block/CU, 8 waves/CU.
// ---------------------------------------------------------------------------
__global__ __launch_bounds__(512) void hist_kernel(const float4* __restrict__ dst4,
                                                   const float4* __restrict__ ref4,
                                                   float* __restrict__ partial) {
    __shared__ unsigned int h[MFINE];   // 8 KB
    const int t  = threadIdx.x;
    const int b  = blockIdx.x;
    const int s  = b >> 6;      // slice 0..3
    const int ib = b & 63;

    for (int i = t; i < MFINE; i += 512) h[i] = 0;
    __syncthreads();

    const float4* src = (s < 2) ? (dst4 + s * (NVOX / 4))
                                : (ref4 + (s - 2) * (NVOX / 4));
    const int base = ib * 4096;   // 4096 float4 per block

    // batch all loads first (8*16B/thread in flight), then LDS atomics
    float4 v[8];
    #pragma unroll
    for (int j = 0; j < 8; ++j) v[j] = src[base + j * 512 + t];

    #pragma unroll
    for (int j = 0; j < 8; ++j) {
        int m0 = min(max((int)(v[j].x * (float)MFINE), 0), MFINE - 1);
        int m1 = min(max((int)(v[j].y * (float)MFINE), 0), MFINE - 1);
        int m2 = min(max((int)(v[j].z * (float)MFINE), 0), MFINE - 1);
        int m3 = min(max((int)(v[j].w * (float)MFINE), 0), MFINE - 1);
        atomicAdd(&h[m0], 1u);
        atomicAdd(&h[m1], 1u);
        atomicAdd(&h[m2], 1u);
        atomicAdd(&h[m3], 1u);
    }
    __syncthreads();

    // ---- per-block conv: 32 bins x 16 lanes each ----
    const int c = t >> 4;       // soft bin 0..31
    const int j = t & 15;
    const float fc = (float)c;
    const float DY = 31.0f / (float)MFINE;     // fine-bin width in y units
    const float c1 = 12.1825190f;              // e^2.5 - e^-2.5
    const float c2 = 12.3467369f;              // e^2.5 + e^-2.5

    int i0 = (int)ceilf((fc - 4.5f) * ((float)MFINE / 31.0f) - 0.5f);
    int i1 = (int)floorf((fc + 4.5f) * ((float)MFINE / 31.0f) - 0.5f);
    if (i0 < 0) i0 = 0;
    if (i1 > MFINE - 1) i1 = MFINE - 1;

    // E = exp(5*d) with d = (i+0.5)*DY - fc; stride 16 => E *= exp(80*DY)
    const float Kstep = __expf(80.0f * DY);
    float d0 = fmaf((float)(i0 + j), DY, 0.5f * DY - fc);
    float E  = __expf(5.0f * d0);

    float acc = 0.f;
    for (int i = i0 + j; i <= i1; i += 16) {
        float cnt = (float)h[i];
        float den = fmaf(E, c2, fmaf(E, E, 1.0f));
        acc = fmaf(cnt * E, c1 * __builtin_amdgcn_rcpf(den), acc);
        E *= Kstep;
    }
    acc += __shfl_xor(acc, 1, 64);
    acc += __shfl_xor(acc, 2, 64);
    acc += __shfl_xor(acc, 4, 64);
    acc += __shfl_xor(acc, 8, 64);
    if (j == 0) partial[(s * BINS + c) * PB + ib] = acc;
}

// ---------------------------------------------------------------------------
// K2: fused table + apply. The 16 voxel loads are issued FIRST (they have no
// dependence on the table phases), so the 8 MiB dst re-read is in flight
// under the serial reduce -> cumsum -> argmin -> LUT chain (T14 async split).
// Every block redundantly (in parallel) reduces the partials for its dst
// slice + matching ref slice (16 KB, L2-resident), does segmented shuffle
// cumsum -> cdf, argmin matching table, builds a 2048-entry LUT of the full
// voxel->output function in LDS, then applies it to 16 voxels/thread with
// linear interpolation.
// ---------------------------------------------------------------------------
__global__ __launch_bounds__(256) void apply_kernel(const float4* __restrict__ dst4,
                                                    const float* __restrict__ partial,
                                                    float4* __restrict__ out4) {
    __shared__ float slut[NLUT];     // 8 KB
    __shared__ float softS[64];      // [0,32) dst bins, [32,64) ref bins
    __shared__ float cdfS[64];
    __shared__ float gS[BINS];       // exp(-k^2/50)
    __shared__ float gtS[BINS];      // g_k * table_k
    const int t  = threadIdx.x;
    const int b  = blockIdx.x;
    const int s  = b >> 8;           // dst slice 0..1
    const int ib = b & 255;

    // ---- issue voxel loads up front; consumed only after the LUT barrier ----
    const int base = s * (NVOX / 4) + ib * 1024;
    float4 v[4];
    #pragma unroll
    for (int j = 0; j < 4; ++j) v[j] = dst4[base + j * 256 + t];

    // ---- reduce partials: 64 rows x 4 lanes, 4 float4 loads per thread ----
    {
        const int r = t >> 2, j = t & 3;
        const int grow = (r < 32) ? (s * BINS + r) : ((2 + s) * BINS + (r - 32));
        const float4* prow = (const float4*)(partial + grow * PB);
        float4 a4 = make_float4(0.f, 0.f, 0.f, 0.f);
        #pragma unroll
        for (int m = 0; m < 4; ++m) {
            float4 p = prow[j + 4 * m];
            a4.x += p.x; a4.y += p.y; a4.z += p.z; a4.w += p.w;
        }
        float acc = (a4.x + a4.y) + (a4.z + a4.w);
        acc += __shfl_xor(acc, 1, 64);
        acc += __shfl_xor(acc, 2, 64);
        if (j == 0) softS[r] = acc;
    }
    __syncthreads();

    // ---- segmented (width-32) shuffle prefix-sum + normalize -> cdf ----
    if (t < 64) {
        float v2 = softS[t];
        #pragma unroll
        for (int off = 1; off < BINS; off <<= 1) {
            float w = __shfl_up(v2, off, 32);
            if ((t & 31) >= off) v2 += w;
        }
        float total = __shfl(v2, 31, 32);
        cdfS[t] = v2 / fmaxf(total, 1e-12f);
    }
    __syncthreads();

    // ---- argmin matching table ----
    if (t < 32) {
        float v2 = cdfS[t];
        int best = 0;
        float bd = fabsf(v2 - cdfS[32]);
        #pragma unroll
        for (int k = 1; k < BINS; ++k) {
            float dk = fabsf(v2 - cdfS[32 + k]);
            if (dk < bd) { bd = dk; best = k; }   // strict < keeps lowest index
        }
        float g = __expf(-(float)(t * t) * (1.0f / 50.0f));
        gtS[t] = g * (float)best;
        gS[t]  = g;
    }
    __syncthreads();

    // ---- LUT: out(x) = (Σ_k u_k g_k t_k)/(Σ_k u_k g_k)/31, u_k = r^k,
    //      r = e^{y/25}, y = x*31, sampled at x = idx/2047 ----
    for (int e = t; e < NLUT; e += 256) {
        float y = (float)e * (31.0f / (float)(NLUT - 1));
        float r = __expf(y * (1.0f / 25.0f));
        float u = 1.f, num = 0.f, den = 0.f;
        #pragma unroll
        for (int k = 0; k < BINS; ++k) {
            num = fmaf(u, gtS[k], num);
            den = fmaf(u, gS[k], den);
            u *= r;
        }
        slut[e] = num * __builtin_amdgcn_rcpf(den) * (1.0f / 31.0f);
    }
    __syncthreads();

    // ---- apply: 16 voxels/thread via LUT + linear interp ----
    float* x = (float*)v;
    #pragma unroll
    for (int i = 0; i < 16; ++i) {
        float p = x[i] * (float)(NLUT - 1);
        p = fminf(fmaxf(p, 0.f), (float)(NLUT - 1) - 1.0f);
        int   ix = (int)p;
        float fr = p - (float)ix;
        float lo = slut[ix], hi = slut[ix + 1];
        x[i] = fmaf(fr, hi - lo, lo);
    }
    #pragma unroll
    for (int j = 0; j < 4; ++j) out4[base + j * 256 + t] = v[j];
}

// ---------------------------------------------------------------------------
extern "C" void kernel_launch(void* const* d_in, const int* in_sizes, int n_in,
                              void* d_out, int out_size, void* d_ws, size_t ws_size,
                              hipStream_t stream) {
    const float4* dst4 = (const float4*)d_in[0];
    const float4* ref4 = (const float4*)d_in[1];
    float4* out4 = (float4*)d_out;
    float* partial = (float*)d_ws;

    hipLaunchKernelGGL(hist_kernel,  dim3(HIST_BLOCKS),  dim3(512), 0, stream,
                       dst4, ref4, partial);
    hipLaunchKernelGGL(apply_kernel, dim3(APPLY_BLOCKS), dim3(256), 0, stream,
                       dst4, partial, out4);
}